// Round 15
// baseline (2615.550 us; speedup 1.0000x reference)
//
#include <hip/hip_runtime.h>

#define IN 10
#define HID 128
#define OUT 4

// Dequantized f32 weights (static device globals; rewritten every launch).
__device__ float g_W1qf[HID * IN];
__device__ float g_W2qf[HID * HID];
__device__ float g_W3qf[OUT * HID];

// ---------- asm-protected f32 ops (immune to fast-math/reassoc/contract) ----------
__device__ __forceinline__ float f_fma(float a, float b, float c) {
    float d; asm("v_fma_f32 %0, %1, %2, %3" : "=v"(d) : "v"(a), "v"(b), "v"(c)); return d;
}
__device__ __forceinline__ float f_fma_s(float a, float w, float c) {   // 1 SGPR legal in VOP3
    float d; asm("v_fma_f32 %0, %1, %2, %3" : "=v"(d) : "v"(a), "s"(w), "v"(c)); return d;
}
__device__ __forceinline__ float f_mul(float a, float b) {
    float d; asm("v_mul_f32 %0, %1, %2" : "=v"(d) : "v"(a), "v"(b)); return d;
}
__device__ __forceinline__ float f_add(float a, float b) {
    float d; asm("v_add_f32 %0, %1, %2" : "=v"(d) : "v"(a), "v"(b)); return d;
}
__device__ __forceinline__ float f_sub(float a, float b) {
    float d; asm("v_sub_f32 %0, %1, %2" : "=v"(d) : "v"(a), "v"(b)); return d;
}
__device__ __forceinline__ float f_rndne(float a) {   // round half to even = np.round
    float d; asm("v_rndne_f32 %0, %1" : "=v"(d) : "v"(a)); return d;
}
__device__ __forceinline__ float f_rcp(float a) {
    float d; asm("v_rcp_f32 %0, %1" : "=v"(d) : "v"(a)); return d;
}
// Exact byte->float converts (values <=255 exact; we use codes <=15).
__device__ __forceinline__ float cvt_ub0(unsigned int u) {
    float d; asm("v_cvt_f32_ubyte0 %0, %1" : "=v"(d) : "v"(u)); return d;
}
__device__ __forceinline__ float cvt_ub1(unsigned int u) {
    float d; asm("v_cvt_f32_ubyte1 %0, %1" : "=v"(d) : "v"(u)); return d;
}
__device__ __forceinline__ float cvt_ub2(unsigned int u) {
    float d; asm("v_cvt_f32_ubyte2 %0, %1" : "=v"(d) : "v"(u)); return d;
}
__device__ __forceinline__ float cvt_ub3(unsigned int u) {
    float d; asm("v_cvt_f32_ubyte3 %0, %1" : "=v"(d) : "v"(u)); return d;
}

// CR reciprocal / CR divide (Markstein). d.y = correctly-rounded 1/s.
struct DivCR { float y, ns; };
__device__ __forceinline__ DivCR make_div(float s) {
    DivCR d;
    d.ns = f_sub(0.0f, s);
    float y0 = f_rcp(s);
    float e0 = f_fma(d.ns, y0, 1.0f);
    float y1 = f_fma(e0, y0, y0);
    float e1 = f_fma(d.ns, y1, 1.0f);
    d.y = f_fma(e1, y1, y1);
    return d;
}
__device__ __forceinline__ float div_cr(float h, DivCR d) {
    float q0 = f_mul(h, d.y);
    float r  = f_fma(d.ns, q0, h);
    return f_fma(r, d.y, q0);
}

// prep: bit-identical to R11-R14 (passed).
__global__ void prep_kernel(const float* __restrict__ W1,
                            const float* __restrict__ W2,
                            const float* __restrict__ W3) {
    __shared__ float red[256];
    __shared__ float sS;
    const int t = threadIdx.x;
    const int which = blockIdx.x;

    const float* W; float* Wo; int n;
    if (which == 0)      { W = W1; Wo = g_W1qf; n = HID * IN; }
    else if (which == 1) { W = W2; Wo = g_W2qf; n = HID * HID; }
    else                 { W = W3; Wo = g_W3qf; n = OUT * HID; }

    float mx = 0.f;
    for (int i = t; i < n; i += 256) mx = fmaxf(mx, fabsf(W[i]));
    red[t] = mx;
    __syncthreads();
    for (int s = 128; s > 0; s >>= 1) {
        if (t < s) red[t] = fmaxf(red[t], red[t + s]);
        __syncthreads();
    }
    if (t == 0) {
        DivCR d7 = make_div(7.0f);
        sS = div_cr(red[0], d7);
    }
    __syncthreads();
    const float s = sS;
    const float rs = make_div(s).y;

    for (int i = t; i < n; i += 256) {
        float r = f_rndne(f_mul(W[i], rs));
        r = fminf(7.f, fmaxf(-7.f, r));
        Wo[i] = f_mul(r, s);
    }
}

// Quant epilogue: h -> uint code (bit-identical op sequence to R11-R14).
__device__ __forceinline__ unsigned int quant_code(float acc, float bias, float recip) {
    float h = f_add(acc, bias);
    float r = f_rndne(f_mul(h, recip));
    r = fminf(15.f, fmaxf(0.f, r));
    return (unsigned int)r;
}

// (256,2): VGPR cap 128 -> 2 blocks/CU (8 waves) with the 64 KB LDS stage.
// act kept as PACKED CODES in 32 VGPRs (no spill at <=128 VGPR); unpacked
// on the fly via exact v_cvt_f32_ubyteN + f_mul (bit-identical act values).
__global__ __launch_bounds__(256, 2) void mlp_kernel(
    const float* __restrict__ m,
    const float* __restrict__ b1,
    const float* __restrict__ b2,
    const float* __restrict__ b3,
    const float* __restrict__ s_act1,
    const float* __restrict__ s_act2,
    float* __restrict__ out, int nrows)
{
    __shared__ float sW2[HID * HID];   // 64 KB

    const int t = threadIdx.x;

    // Cooperative stage (coalesced float4), BEFORE any early-out.
    {
        const float4* src = (const float4*)g_W2qf;
        float4* dst = (float4*)sW2;
        #pragma unroll
        for (int i = 0; i < 16; ++i) dst[t + 256 * i] = src[t + 256 * i];
    }
    __syncthreads();

    const int row = blockIdx.x * 256 + t;
    if (row >= nrows) return;               // no barriers below

    const float s1 = s_act1[0];
    const float s2 = s_act2[0];
    const float r1 = make_div(s1).y;        // CR 1/s1
    const float r2 = make_div(s2).y;        // CR 1/s2

    float x[IN];
    const float2* mr = (const float2*)(m + (size_t)row * IN);
    #pragma unroll
    for (int i = 0; i < 5; ++i) {
        float2 v = mr[i];
        x[2 * i] = v.x; x[2 * i + 1] = v.y;
    }

    // ---- Layer 1: 4-way j-ILP chains -> packed codes in 32 VGPRs ----
    unsigned int actw[32];
    #pragma unroll
    for (int g = 0; g < 32; ++g) {
        const float* w0 = &g_W1qf[(4 * g + 0) * IN];
        const float* w1 = &g_W1qf[(4 * g + 1) * IN];
        const float* w2 = &g_W1qf[(4 * g + 2) * IN];
        const float* w3 = &g_W1qf[(4 * g + 3) * IN];
        float a0 = f_fma_s(x[0], w0[0], 0.0f);
        float a1c = f_fma_s(x[0], w1[0], 0.0f);
        float a2c = f_fma_s(x[0], w2[0], 0.0f);
        float a3c = f_fma_s(x[0], w3[0], 0.0f);
        #pragma unroll
        for (int k = 1; k < IN; ++k) {
            a0  = f_fma_s(x[k], w0[k], a0);
            a1c = f_fma_s(x[k], w1[k], a1c);
            a2c = f_fma_s(x[k], w2[k], a2c);
            a3c = f_fma_s(x[k], w3[k], a3c);
        }
        unsigned int c0 = quant_code(a0,  b1[4 * g + 0], r1);
        unsigned int c1 = quant_code(a1c, b1[4 * g + 1], r1);
        unsigned int c2 = quant_code(a2c, b1[4 * g + 2], r1);
        unsigned int c3 = quant_code(a3c, b1[4 * g + 3], r1);
        actw[g] = c0 | (c1 << 8) | (c2 << 16) | (c3 << 24);
    }

    // ---- Layer 2 (LDS weights, 4-way j-ILP, on-the-fly act unpack) + fused L3 ----
    float o0 = 0.0f, o1 = 0.0f, o2 = 0.0f, o3 = 0.0f;

    #pragma unroll 1
    for (int g = 0; g < 32; ++g) {
        const float4* w0 = (const float4*)&sW2[(4 * g + 0) * HID];
        const float4* w1 = (const float4*)&sW2[(4 * g + 1) * HID];
        const float4* w2 = (const float4*)&sW2[(4 * g + 2) * HID];
        const float4* w3 = (const float4*)&sW2[(4 * g + 3) * HID];
        float a0 = 0.0f, a1c = 0.0f, a2c = 0.0f, a3c = 0.0f;
        #pragma unroll
        for (int kk = 0; kk < 32; ++kk) {
            float4 q0 = w0[kk];
            float4 q1 = w1[kk];
            float4 q2 = w2[kk];
            float4 q3 = w3[kk];
            const unsigned int u = actw[kk];          // static index -> VGPR
            float v0 = f_mul(cvt_ub0(u), s1);         // == f_mul((float)c, s1): exact
            float v1 = f_mul(cvt_ub1(u), s1);
            float v2 = f_mul(cvt_ub2(u), s1);
            float v3 = f_mul(cvt_ub3(u), s1);
            a0  = f_fma(v0, q0.x, a0);
            a1c = f_fma(v0, q1.x, a1c);
            a2c = f_fma(v0, q2.x, a2c);
            a3c = f_fma(v0, q3.x, a3c);
            a0  = f_fma(v1, q0.y, a0);
            a1c = f_fma(v1, q1.y, a1c);
            a2c = f_fma(v1, q2.y, a2c);
            a3c = f_fma(v1, q3.y, a3c);
            a0  = f_fma(v2, q0.z, a0);
            a1c = f_fma(v2, q1.z, a1c);
            a2c = f_fma(v2, q2.z, a2c);
            a3c = f_fma(v2, q3.z, a3c);
            a0  = f_fma(v3, q0.w, a0);
            a1c = f_fma(v3, q1.w, a1c);
            a2c = f_fma(v3, q2.w, a2c);
            a3c = f_fma(v3, q3.w, a3c);
        }
        unsigned int c0 = quant_code(a0,  b2[4 * g + 0], r2);
        unsigned int c1 = quant_code(a1c, b2[4 * g + 1], r2);
        unsigned int c2 = quant_code(a2c, b2[4 * g + 2], r2);
        unsigned int c3 = quant_code(a3c, b2[4 * g + 3], r2);
        float v0 = f_mul((float)c0, s2);
        float v1 = f_mul((float)c1, s2);
        float v2 = f_mul((float)c2, s2);
        float v3 = f_mul((float)c3, s2);
        // Fused L3: ascending k = 4g..4g+3 appended to each output chain.
        o0 = f_fma_s(v0, g_W3qf[0 * HID + 4 * g + 0], o0);
        o1 = f_fma_s(v0, g_W3qf[1 * HID + 4 * g + 0], o1);
        o2 = f_fma_s(v0, g_W3qf[2 * HID + 4 * g + 0], o2);
        o3 = f_fma_s(v0, g_W3qf[3 * HID + 4 * g + 0], o3);
        o0 = f_fma_s(v1, g_W3qf[0 * HID + 4 * g + 1], o0);
        o1 = f_fma_s(v1, g_W3qf[1 * HID + 4 * g + 1], o1);
        o2 = f_fma_s(v1, g_W3qf[2 * HID + 4 * g + 1], o2);
        o3 = f_fma_s(v1, g_W3qf[3 * HID + 4 * g + 1], o3);
        o0 = f_fma_s(v2, g_W3qf[0 * HID + 4 * g + 2], o0);
        o1 = f_fma_s(v2, g_W3qf[1 * HID + 4 * g + 2], o1);
        o2 = f_fma_s(v2, g_W3qf[2 * HID + 4 * g + 2], o2);
        o3 = f_fma_s(v2, g_W3qf[3 * HID + 4 * g + 2], o3);
        o0 = f_fma_s(v3, g_W3qf[0 * HID + 4 * g + 3], o0);
        o1 = f_fma_s(v3, g_W3qf[1 * HID + 4 * g + 3], o1);
        o2 = f_fma_s(v3, g_W3qf[2 * HID + 4 * g + 3], o2);
        o3 = f_fma_s(v3, g_W3qf[3 * HID + 4 * g + 3], o3);
    }

    float4 o;
    o.x = f_add(o0, b3[0]);
    o.y = f_add(o1, b3[1]);
    o.z = f_add(o2, b3[2]);
    o.w = f_add(o3, b3[3]);
    *(float4*)(out + (size_t)row * OUT) = o;
}

extern "C" void kernel_launch(void* const* d_in, const int* in_sizes, int n_in,
                              void* d_out, int out_size, void* d_ws, size_t ws_size,
                              hipStream_t stream) {
    const float* m  = (const float*)d_in[0];
    const float* W1 = (const float*)d_in[1];
    const float* b1 = (const float*)d_in[2];
    const float* W2 = (const float*)d_in[3];
    const float* b2 = (const float*)d_in[4];
    const float* W3 = (const float*)d_in[5];
    const float* b3 = (const float*)d_in[6];
    const float* s1 = (const float*)d_in[7];
    const float* s2 = (const float*)d_in[8];
    const int nrows = in_sizes[0] / IN;

    prep_kernel<<<3, 256, 0, stream>>>(W1, W2, W3);
    const int nblk = (nrows + 255) / 256;
    mlp_kernel<<<nblk, 256, 0, stream>>>(m, b1, b2, b3, s1, s2, (float*)d_out, nrows);
}

// Round 16
// 1604.134 us; speedup vs baseline: 1.6305x; 1.6305x over previous
//
#include <hip/hip_runtime.h>

#define IN 10
#define HID 128
#define OUT 4

// Dequantized f32 weights (static device globals; rewritten every launch).
__device__ float g_W1qf[HID * IN];
__device__ float g_W2qf[HID * HID];
__device__ float g_W3qf[OUT * HID];

// ---------- asm-protected f32 ops (immune to fast-math/reassoc/contract) ----------
__device__ __forceinline__ float f_fma(float a, float b, float c) {
    float d; asm("v_fma_f32 %0, %1, %2, %3" : "=v"(d) : "v"(a), "v"(b), "v"(c)); return d;
}
__device__ __forceinline__ float f_fma_s(float a, float w, float c) {   // 1 SGPR legal in VOP3
    float d; asm("v_fma_f32 %0, %1, %2, %3" : "=v"(d) : "v"(a), "s"(w), "v"(c)); return d;
}
__device__ __forceinline__ float f_mul(float a, float b) {
    float d; asm("v_mul_f32 %0, %1, %2" : "=v"(d) : "v"(a), "v"(b)); return d;
}
__device__ __forceinline__ float f_add(float a, float b) {
    float d; asm("v_add_f32 %0, %1, %2" : "=v"(d) : "v"(a), "v"(b)); return d;
}
__device__ __forceinline__ float f_sub(float a, float b) {
    float d; asm("v_sub_f32 %0, %1, %2" : "=v"(d) : "v"(a), "v"(b)); return d;
}
__device__ __forceinline__ float f_rndne(float a) {   // round half to even = np.round
    float d; asm("v_rndne_f32 %0, %1" : "=v"(d) : "v"(a)); return d;
}
__device__ __forceinline__ float f_rcp(float a) {
    float d; asm("v_rcp_f32 %0, %1" : "=v"(d) : "v"(a)); return d;
}
// Exact byte->float converts (values <=255 exact; we use codes <=15).
__device__ __forceinline__ float cvt_ub0(unsigned int u) {
    float d; asm("v_cvt_f32_ubyte0 %0, %1" : "=v"(d) : "v"(u)); return d;
}
__device__ __forceinline__ float cvt_ub1(unsigned int u) {
    float d; asm("v_cvt_f32_ubyte1 %0, %1" : "=v"(d) : "v"(u)); return d;
}
__device__ __forceinline__ float cvt_ub2(unsigned int u) {
    float d; asm("v_cvt_f32_ubyte2 %0, %1" : "=v"(d) : "v"(u)); return d;
}
__device__ __forceinline__ float cvt_ub3(unsigned int u) {
    float d; asm("v_cvt_f32_ubyte3 %0, %1" : "=v"(d) : "v"(u)); return d;
}

// CR reciprocal / CR divide (Markstein). d.y = correctly-rounded 1/s.
struct DivCR { float y, ns; };
__device__ __forceinline__ DivCR make_div(float s) {
    DivCR d;
    d.ns = f_sub(0.0f, s);
    float y0 = f_rcp(s);
    float e0 = f_fma(d.ns, y0, 1.0f);
    float y1 = f_fma(e0, y0, y0);
    float e1 = f_fma(d.ns, y1, 1.0f);
    d.y = f_fma(e1, y1, y1);
    return d;
}
__device__ __forceinline__ float div_cr(float h, DivCR d) {
    float q0 = f_mul(h, d.y);
    float r  = f_fma(d.ns, q0, h);
    return f_fma(r, d.y, q0);
}

// prep: bit-identical to R11-R15 (passed).
__global__ void prep_kernel(const float* __restrict__ W1,
                            const float* __restrict__ W2,
                            const float* __restrict__ W3) {
    __shared__ float red[256];
    __shared__ float sS;
    const int t = threadIdx.x;
    const int which = blockIdx.x;

    const float* W; float* Wo; int n;
    if (which == 0)      { W = W1; Wo = g_W1qf; n = HID * IN; }
    else if (which == 1) { W = W2; Wo = g_W2qf; n = HID * HID; }
    else                 { W = W3; Wo = g_W3qf; n = OUT * HID; }

    float mx = 0.f;
    for (int i = t; i < n; i += 256) mx = fmaxf(mx, fabsf(W[i]));
    red[t] = mx;
    __syncthreads();
    for (int s = 128; s > 0; s >>= 1) {
        if (t < s) red[t] = fmaxf(red[t], red[t + s]);
        __syncthreads();
    }
    if (t == 0) {
        DivCR d7 = make_div(7.0f);
        sS = div_cr(red[0], d7);
    }
    __syncthreads();
    const float s = sS;
    const float rs = make_div(s).y;

    for (int i = t; i < n; i += 256) {
        float r = f_rndne(f_mul(W[i], rs));
        r = fminf(7.f, fmaxf(-7.f, r));
        Wo[i] = f_mul(r, s);
    }
}

// Quant epilogue: h -> uint code (bit-identical op sequence to R11-R15).
__device__ __forceinline__ unsigned int quant_code(float acc, float bias, float recip) {
    float h = f_add(acc, bias);
    float r = f_rndne(f_mul(h, recip));
    r = fminf(15.f, fmaxf(0.f, r));
    return (unsigned int)r;
}

// (256,2): VGPR cap 128, 2 blocks/CU with the 64 KB LDS stage. act kept as
// PACKED CODES in 32 VGPRs; sched_barrier fences stop the scheduler from
// hoisting all ds_reads (R15's 5 GB scratch spill) -> live set ~110 regs.
__global__ __launch_bounds__(256, 2) void mlp_kernel(
    const float* __restrict__ m,
    const float* __restrict__ b1,
    const float* __restrict__ b2,
    const float* __restrict__ b3,
    const float* __restrict__ s_act1,
    const float* __restrict__ s_act2,
    float* __restrict__ out, int nrows)
{
    __shared__ float sW2[HID * HID];   // 64 KB

    const int t = threadIdx.x;

    // Cooperative stage (coalesced float4), BEFORE any early-out.
    {
        const float4* src = (const float4*)g_W2qf;
        float4* dst = (float4*)sW2;
        #pragma unroll
        for (int i = 0; i < 16; ++i) dst[t + 256 * i] = src[t + 256 * i];
    }
    __syncthreads();

    const int row = blockIdx.x * 256 + t;
    if (row >= nrows) return;               // no barriers below

    const float s1 = s_act1[0];
    const float s2 = s_act2[0];
    const float r1 = make_div(s1).y;        // CR 1/s1
    const float r2 = make_div(s2).y;        // CR 1/s2

    float x[IN];
    const float2* mr = (const float2*)(m + (size_t)row * IN);
    #pragma unroll
    for (int i = 0; i < 5; ++i) {
        float2 v = mr[i];
        x[2 * i] = v.x; x[2 * i + 1] = v.y;
    }

    // ---- Layer 1: 4-way j-ILP chains -> packed codes in 32 VGPRs ----
    unsigned int actw[32];
    #pragma unroll
    for (int g = 0; g < 32; ++g) {
        const float* w0 = &g_W1qf[(4 * g + 0) * IN];
        const float* w1 = &g_W1qf[(4 * g + 1) * IN];
        const float* w2 = &g_W1qf[(4 * g + 2) * IN];
        const float* w3 = &g_W1qf[(4 * g + 3) * IN];
        float a0 = f_fma_s(x[0], w0[0], 0.0f);
        float a1c = f_fma_s(x[0], w1[0], 0.0f);
        float a2c = f_fma_s(x[0], w2[0], 0.0f);
        float a3c = f_fma_s(x[0], w3[0], 0.0f);
        #pragma unroll
        for (int k = 1; k < IN; ++k) {
            a0  = f_fma_s(x[k], w0[k], a0);
            a1c = f_fma_s(x[k], w1[k], a1c);
            a2c = f_fma_s(x[k], w2[k], a2c);
            a3c = f_fma_s(x[k], w3[k], a3c);
        }
        unsigned int c0 = quant_code(a0,  b1[4 * g + 0], r1);
        unsigned int c1 = quant_code(a1c, b1[4 * g + 1], r1);
        unsigned int c2 = quant_code(a2c, b1[4 * g + 2], r1);
        unsigned int c3 = quant_code(a3c, b1[4 * g + 3], r1);
        actw[g] = c0 | (c1 << 8) | (c2 << 16) | (c3 << 24);
        __builtin_amdgcn_sched_barrier(0);   // bound L1 live ranges
    }

    // ---- Layer 2 (LDS weights, 4-way j-ILP, on-the-fly act unpack) + fused L3 ----
    float o0 = 0.0f, o1 = 0.0f, o2 = 0.0f, o3 = 0.0f;

    #pragma unroll 1
    for (int g = 0; g < 32; ++g) {
        const float4* w0 = (const float4*)&sW2[(4 * g + 0) * HID];
        const float4* w1 = (const float4*)&sW2[(4 * g + 1) * HID];
        const float4* w2 = (const float4*)&sW2[(4 * g + 2) * HID];
        const float4* w3 = (const float4*)&sW2[(4 * g + 3) * HID];
        float a0 = 0.0f, a1c = 0.0f, a2c = 0.0f, a3c = 0.0f;
        #pragma unroll
        for (int kp = 0; kp < 16; ++kp) {            // pairs of kk: fence window
            #pragma unroll
            for (int kh = 0; kh < 2; ++kh) {
                const int kk = 2 * kp + kh;          // compile-time constant
                float4 q0 = w0[kk];
                float4 q1 = w1[kk];
                float4 q2 = w2[kk];
                float4 q3 = w3[kk];
                const unsigned int u = actw[kk];     // static index -> VGPR
                float v0 = f_mul(cvt_ub0(u), s1);    // == f_mul((float)c, s1): exact
                float v1 = f_mul(cvt_ub1(u), s1);
                float v2 = f_mul(cvt_ub2(u), s1);
                float v3 = f_mul(cvt_ub3(u), s1);
                a0  = f_fma(v0, q0.x, a0);
                a1c = f_fma(v0, q1.x, a1c);
                a2c = f_fma(v0, q2.x, a2c);
                a3c = f_fma(v0, q3.x, a3c);
                a0  = f_fma(v1, q0.y, a0);
                a1c = f_fma(v1, q1.y, a1c);
                a2c = f_fma(v1, q2.y, a2c);
                a3c = f_fma(v1, q3.y, a3c);
                a0  = f_fma(v2, q0.z, a0);
                a1c = f_fma(v2, q1.z, a1c);
                a2c = f_fma(v2, q2.z, a2c);
                a3c = f_fma(v2, q3.z, a3c);
                a0  = f_fma(v3, q0.w, a0);
                a1c = f_fma(v3, q1.w, a1c);
                a2c = f_fma(v3, q2.w, a2c);
                a3c = f_fma(v3, q3.w, a3c);
            }
            __builtin_amdgcn_sched_barrier(0);       // cap staged ds_reads at 8xfloat4
        }
        unsigned int c0 = quant_code(a0,  b2[4 * g + 0], r2);
        unsigned int c1 = quant_code(a1c, b2[4 * g + 1], r2);
        unsigned int c2 = quant_code(a2c, b2[4 * g + 2], r2);
        unsigned int c3 = quant_code(a3c, b2[4 * g + 3], r2);
        float v0 = f_mul((float)c0, s2);
        float v1 = f_mul((float)c1, s2);
        float v2 = f_mul((float)c2, s2);
        float v3 = f_mul((float)c3, s2);
        // Fused L3: ascending k = 4g..4g+3 appended to each output chain.
        o0 = f_fma_s(v0, g_W3qf[0 * HID + 4 * g + 0], o0);
        o1 = f_fma_s(v0, g_W3qf[1 * HID + 4 * g + 0], o1);
        o2 = f_fma_s(v0, g_W3qf[2 * HID + 4 * g + 0], o2);
        o3 = f_fma_s(v0, g_W3qf[3 * HID + 4 * g + 0], o3);
        o0 = f_fma_s(v1, g_W3qf[0 * HID + 4 * g + 1], o0);
        o1 = f_fma_s(v1, g_W3qf[1 * HID + 4 * g + 1], o1);
        o2 = f_fma_s(v1, g_W3qf[2 * HID + 4 * g + 1], o2);
        o3 = f_fma_s(v1, g_W3qf[3 * HID + 4 * g + 1], o3);
        o0 = f_fma_s(v2, g_W3qf[0 * HID + 4 * g + 2], o0);
        o1 = f_fma_s(v2, g_W3qf[1 * HID + 4 * g + 2], o1);
        o2 = f_fma_s(v2, g_W3qf[2 * HID + 4 * g + 2], o2);
        o3 = f_fma_s(v2, g_W3qf[3 * HID + 4 * g + 2], o3);
        o0 = f_fma_s(v3, g_W3qf[0 * HID + 4 * g + 3], o0);
        o1 = f_fma_s(v3, g_W3qf[1 * HID + 4 * g + 3], o1);
        o2 = f_fma_s(v3, g_W3qf[2 * HID + 4 * g + 3], o2);
        o3 = f_fma_s(v3, g_W3qf[3 * HID + 4 * g + 3], o3);
    }

    float4 o;
    o.x = f_add(o0, b3[0]);
    o.y = f_add(o1, b3[1]);
    o.z = f_add(o2, b3[2]);
    o.w = f_add(o3, b3[3]);
    *(float4*)(out + (size_t)row * OUT) = o;
}

extern "C" void kernel_launch(void* const* d_in, const int* in_sizes, int n_in,
                              void* d_out, int out_size, void* d_ws, size_t ws_size,
                              hipStream_t stream) {
    const float* m  = (const float*)d_in[0];
    const float* W1 = (const float*)d_in[1];
    const float* b1 = (const float*)d_in[2];
    const float* W2 = (const float*)d_in[3];
    const float* b2 = (const float*)d_in[4];
    const float* W3 = (const float*)d_in[5];
    const float* b3 = (const float*)d_in[6];
    const float* s1 = (const float*)d_in[7];
    const float* s2 = (const float*)d_in[8];
    const int nrows = in_sizes[0] / IN;

    prep_kernel<<<3, 256, 0, stream>>>(W1, W2, W3);
    const int nblk = (nrows + 255) / 256;
    mlp_kernel<<<nblk, 256, 0, stream>>>(m, b1, b2, b3, s1, s2, (float*)d_out, nrows);
}

// Round 17
// 1171.548 us; speedup vs baseline: 2.2326x; 1.3692x over previous
//
#include <hip/hip_runtime.h>

#define IN 10
#define HID 128
#define OUT 4

// Dequantized f32 weights (static device globals; rewritten every launch).
__device__ float g_W1qf[HID * IN];
__device__ float g_W2qf[HID * HID];
__device__ float g_W3qf[OUT * HID];

// ---------- asm-protected f32 ops (immune to fast-math/reassoc/contract) ----------
__device__ __forceinline__ float f_fma(float a, float b, float c) {
    float d; asm("v_fma_f32 %0, %1, %2, %3" : "=v"(d) : "v"(a), "v"(b), "v"(c)); return d;
}
__device__ __forceinline__ float f_fma_s(float a, float w, float c) {   // 1 SGPR legal in VOP3
    float d; asm("v_fma_f32 %0, %1, %2, %3" : "=v"(d) : "v"(a), "s"(w), "v"(c)); return d;
}
__device__ __forceinline__ float f_mul(float a, float b) {
    float d; asm("v_mul_f32 %0, %1, %2" : "=v"(d) : "v"(a), "v"(b)); return d;
}
__device__ __forceinline__ float f_add(float a, float b) {
    float d; asm("v_add_f32 %0, %1, %2" : "=v"(d) : "v"(a), "v"(b)); return d;
}
__device__ __forceinline__ float f_sub(float a, float b) {
    float d; asm("v_sub_f32 %0, %1, %2" : "=v"(d) : "v"(a), "v"(b)); return d;
}
__device__ __forceinline__ float f_rndne(float a) {   // round half to even = np.round
    float d; asm("v_rndne_f32 %0, %1" : "=v"(d) : "v"(a)); return d;
}
__device__ __forceinline__ float f_rcp(float a) {
    float d; asm("v_rcp_f32 %0, %1" : "=v"(d) : "v"(a)); return d;
}
// Exact byte->float converts (values <=255 exact; we use codes <=15).
__device__ __forceinline__ float cvt_ub0(unsigned int u) {
    float d; asm("v_cvt_f32_ubyte0 %0, %1" : "=v"(d) : "v"(u)); return d;
}
__device__ __forceinline__ float cvt_ub1(unsigned int u) {
    float d; asm("v_cvt_f32_ubyte1 %0, %1" : "=v"(d) : "v"(u)); return d;
}
__device__ __forceinline__ float cvt_ub2(unsigned int u) {
    float d; asm("v_cvt_f32_ubyte2 %0, %1" : "=v"(d) : "v"(u)); return d;
}
__device__ __forceinline__ float cvt_ub3(unsigned int u) {
    float d; asm("v_cvt_f32_ubyte3 %0, %1" : "=v"(d) : "v"(u)); return d;
}

// CR reciprocal / CR divide (Markstein). d.y = correctly-rounded 1/s.
struct DivCR { float y, ns; };
__device__ __forceinline__ DivCR make_div(float s) {
    DivCR d;
    d.ns = f_sub(0.0f, s);
    float y0 = f_rcp(s);
    float e0 = f_fma(d.ns, y0, 1.0f);
    float y1 = f_fma(e0, y0, y0);
    float e1 = f_fma(d.ns, y1, 1.0f);
    d.y = f_fma(e1, y1, y1);
    return d;
}
__device__ __forceinline__ float div_cr(float h, DivCR d) {
    float q0 = f_mul(h, d.y);
    float r  = f_fma(d.ns, q0, h);
    return f_fma(r, d.y, q0);
}

// prep: bit-identical to R11-R16 (passed).
__global__ void prep_kernel(const float* __restrict__ W1,
                            const float* __restrict__ W2,
                            const float* __restrict__ W3) {
    __shared__ float red[256];
    __shared__ float sS;
    const int t = threadIdx.x;
    const int which = blockIdx.x;

    const float* W; float* Wo; int n;
    if (which == 0)      { W = W1; Wo = g_W1qf; n = HID * IN; }
    else if (which == 1) { W = W2; Wo = g_W2qf; n = HID * HID; }
    else                 { W = W3; Wo = g_W3qf; n = OUT * HID; }

    float mx = 0.f;
    for (int i = t; i < n; i += 256) mx = fmaxf(mx, fabsf(W[i]));
    red[t] = mx;
    __syncthreads();
    for (int s = 128; s > 0; s >>= 1) {
        if (t < s) red[t] = fmaxf(red[t], red[t + s]);
        __syncthreads();
    }
    if (t == 0) {
        DivCR d7 = make_div(7.0f);
        sS = div_cr(red[0], d7);
    }
    __syncthreads();
    const float s = sS;
    const float rs = make_div(s).y;

    for (int i = t; i < n; i += 256) {
        float r = f_rndne(f_mul(W[i], rs));
        r = fminf(7.f, fmaxf(-7.f, r));
        Wo[i] = f_mul(r, s);
    }
}

// Quant epilogue: h -> uint code (bit-identical op sequence to R11-R16).
__device__ __forceinline__ unsigned int quant_code(float acc, float bias, float recip) {
    float h = f_add(acc, bias);
    float r = f_rndne(f_mul(h, recip));
    r = fminf(15.f, fmaxf(0.f, r));
    return (unsigned int)r;
}

// 512-thread blocks: LDS is the occupancy cap (64 KB/block -> 2 blocks/CU),
// so bigger blocks double waves/CU: 16 waves/CU vs R16's 8, same 128-VGPR cap
// (launch_bounds(512,4) -> 128). Per-thread code identical to R16.
__global__ __launch_bounds__(512, 4) void mlp_kernel(
    const float* __restrict__ m,
    const float* __restrict__ b1,
    const float* __restrict__ b2,
    const float* __restrict__ b3,
    const float* __restrict__ s_act1,
    const float* __restrict__ s_act2,
    float* __restrict__ out, int nrows)
{
    __shared__ float sW2[HID * HID];   // 64 KB

    const int t = threadIdx.x;

    // Cooperative stage (coalesced float4), BEFORE any early-out.
    {
        const float4* src = (const float4*)g_W2qf;
        float4* dst = (float4*)sW2;
        #pragma unroll
        for (int i = 0; i < 8; ++i) dst[t + 512 * i] = src[t + 512 * i];
    }
    __syncthreads();

    const int row = blockIdx.x * 512 + t;
    if (row >= nrows) return;               // no barriers below

    const float s1 = s_act1[0];
    const float s2 = s_act2[0];
    const float r1 = make_div(s1).y;        // CR 1/s1
    const float r2 = make_div(s2).y;        // CR 1/s2

    float x[IN];
    const float2* mr = (const float2*)(m + (size_t)row * IN);
    #pragma unroll
    for (int i = 0; i < 5; ++i) {
        float2 v = mr[i];
        x[2 * i] = v.x; x[2 * i + 1] = v.y;
    }

    // ---- Layer 1: 4-way j-ILP chains -> packed codes in 32 VGPRs ----
    unsigned int actw[32];
    #pragma unroll
    for (int g = 0; g < 32; ++g) {
        const float* w0 = &g_W1qf[(4 * g + 0) * IN];
        const float* w1 = &g_W1qf[(4 * g + 1) * IN];
        const float* w2 = &g_W1qf[(4 * g + 2) * IN];
        const float* w3 = &g_W1qf[(4 * g + 3) * IN];
        float a0 = f_fma_s(x[0], w0[0], 0.0f);
        float a1c = f_fma_s(x[0], w1[0], 0.0f);
        float a2c = f_fma_s(x[0], w2[0], 0.0f);
        float a3c = f_fma_s(x[0], w3[0], 0.0f);
        #pragma unroll
        for (int k = 1; k < IN; ++k) {
            a0  = f_fma_s(x[k], w0[k], a0);
            a1c = f_fma_s(x[k], w1[k], a1c);
            a2c = f_fma_s(x[k], w2[k], a2c);
            a3c = f_fma_s(x[k], w3[k], a3c);
        }
        unsigned int c0 = quant_code(a0,  b1[4 * g + 0], r1);
        unsigned int c1 = quant_code(a1c, b1[4 * g + 1], r1);
        unsigned int c2 = quant_code(a2c, b1[4 * g + 2], r1);
        unsigned int c3 = quant_code(a3c, b1[4 * g + 3], r1);
        actw[g] = c0 | (c1 << 8) | (c2 << 16) | (c3 << 24);
        __builtin_amdgcn_sched_barrier(0);   // bound L1 live ranges
    }

    // ---- Layer 2 (LDS weights, 4-way j-ILP, on-the-fly act unpack) + fused L3 ----
    float o0 = 0.0f, o1 = 0.0f, o2 = 0.0f, o3 = 0.0f;

    #pragma unroll 1
    for (int g = 0; g < 32; ++g) {
        const float4* w0 = (const float4*)&sW2[(4 * g + 0) * HID];
        const float4* w1 = (const float4*)&sW2[(4 * g + 1) * HID];
        const float4* w2 = (const float4*)&sW2[(4 * g + 2) * HID];
        const float4* w3 = (const float4*)&sW2[(4 * g + 3) * HID];
        float a0 = 0.0f, a1c = 0.0f, a2c = 0.0f, a3c = 0.0f;
        #pragma unroll
        for (int kp = 0; kp < 16; ++kp) {            // pairs of kk: fence window
            #pragma unroll
            for (int kh = 0; kh < 2; ++kh) {
                const int kk = 2 * kp + kh;          // compile-time constant
                float4 q0 = w0[kk];
                float4 q1 = w1[kk];
                float4 q2 = w2[kk];
                float4 q3 = w3[kk];
                const unsigned int u = actw[kk];     // static index -> VGPR
                float v0 = f_mul(cvt_ub0(u), s1);    // == f_mul((float)c, s1): exact
                float v1 = f_mul(cvt_ub1(u), s1);
                float v2 = f_mul(cvt_ub2(u), s1);
                float v3 = f_mul(cvt_ub3(u), s1);
                a0  = f_fma(v0, q0.x, a0);
                a1c = f_fma(v0, q1.x, a1c);
                a2c = f_fma(v0, q2.x, a2c);
                a3c = f_fma(v0, q3.x, a3c);
                a0  = f_fma(v1, q0.y, a0);
                a1c = f_fma(v1, q1.y, a1c);
                a2c = f_fma(v1, q2.y, a2c);
                a3c = f_fma(v1, q3.y, a3c);
                a0  = f_fma(v2, q0.z, a0);
                a1c = f_fma(v2, q1.z, a1c);
                a2c = f_fma(v2, q2.z, a2c);
                a3c = f_fma(v2, q3.z, a3c);
                a0  = f_fma(v3, q0.w, a0);
                a1c = f_fma(v3, q1.w, a1c);
                a2c = f_fma(v3, q2.w, a2c);
                a3c = f_fma(v3, q3.w, a3c);
            }
            __builtin_amdgcn_sched_barrier(0);       // cap staged ds_reads at 8xfloat4
        }
        unsigned int c0 = quant_code(a0,  b2[4 * g + 0], r2);
        unsigned int c1 = quant_code(a1c, b2[4 * g + 1], r2);
        unsigned int c2 = quant_code(a2c, b2[4 * g + 2], r2);
        unsigned int c3 = quant_code(a3c, b2[4 * g + 3], r2);
        float v0 = f_mul((float)c0, s2);
        float v1 = f_mul((float)c1, s2);
        float v2 = f_mul((float)c2, s2);
        float v3 = f_mul((float)c3, s2);
        // Fused L3: ascending k = 4g..4g+3 appended to each output chain.
        o0 = f_fma_s(v0, g_W3qf[0 * HID + 4 * g + 0], o0);
        o1 = f_fma_s(v0, g_W3qf[1 * HID + 4 * g + 0], o1);
        o2 = f_fma_s(v0, g_W3qf[2 * HID + 4 * g + 0], o2);
        o3 = f_fma_s(v0, g_W3qf[3 * HID + 4 * g + 0], o3);
        o0 = f_fma_s(v1, g_W3qf[0 * HID + 4 * g + 1], o0);
        o1 = f_fma_s(v1, g_W3qf[1 * HID + 4 * g + 1], o1);
        o2 = f_fma_s(v1, g_W3qf[2 * HID + 4 * g + 1], o2);
        o3 = f_fma_s(v1, g_W3qf[3 * HID + 4 * g + 1], o3);
        o0 = f_fma_s(v2, g_W3qf[0 * HID + 4 * g + 2], o0);
        o1 = f_fma_s(v2, g_W3qf[1 * HID + 4 * g + 2], o1);
        o2 = f_fma_s(v2, g_W3qf[2 * HID + 4 * g + 2], o2);
        o3 = f_fma_s(v2, g_W3qf[3 * HID + 4 * g + 2], o3);
        o0 = f_fma_s(v3, g_W3qf[0 * HID + 4 * g + 3], o0);
        o1 = f_fma_s(v3, g_W3qf[1 * HID + 4 * g + 3], o1);
        o2 = f_fma_s(v3, g_W3qf[2 * HID + 4 * g + 3], o2);
        o3 = f_fma_s(v3, g_W3qf[3 * HID + 4 * g + 3], o3);
    }

    float4 o;
    o.x = f_add(o0, b3[0]);
    o.y = f_add(o1, b3[1]);
    o.z = f_add(o2, b3[2]);
    o.w = f_add(o3, b3[3]);
    *(float4*)(out + (size_t)row * OUT) = o;
}

extern "C" void kernel_launch(void* const* d_in, const int* in_sizes, int n_in,
                              void* d_out, int out_size, void* d_ws, size_t ws_size,
                              hipStream_t stream) {
    const float* m  = (const float*)d_in[0];
    const float* W1 = (const float*)d_in[1];
    const float* b1 = (const float*)d_in[2];
    const float* W2 = (const float*)d_in[3];
    const float* b2 = (const float*)d_in[4];
    const float* W3 = (const float*)d_in[5];
    const float* b3 = (const float*)d_in[6];
    const float* s1 = (const float*)d_in[7];
    const float* s2 = (const float*)d_in[8];
    const int nrows = in_sizes[0] / IN;

    prep_kernel<<<3, 256, 0, stream>>>(W1, W2, W3);
    const int nblk = (nrows + 511) / 512;
    mlp_kernel<<<nblk, 512, 0, stream>>>(m, b1, b2, b3, s1, s2, (float*)d_out, nrows);
}